// Round 16
// baseline (326.151 us; speedup 1.0000x reference)
//
#include <hip/hip_runtime.h>

#define RR 3
#define NN 50000
#define EE 800000
#define FF 128
#define DD 128
#define AA 64
#define EPSF 1e-5f
#define RN (RR * NN)
#define RE (RR * EE)
#define NTPR ((NN + 127) / 128)     // 391 dst-tiles (128 nodes) per relation
#define NBK (RR * NTPR)             // 1173 buckets
#define ECHUNK 8192                 // edges per bucketing block
#define NEBLK ((RE + ECHUNK - 1) / ECHUNK)   // 293
#define NTILES (NN / 16)            // 3125 exact
#define FBLK ((NN * 16 + 255) / 256)         // 3125 feat-conversion blocks

typedef __attribute__((ext_vector_type(8))) short bf16x8;
typedef __attribute__((ext_vector_type(4))) float f32x4;
typedef __attribute__((ext_vector_type(2))) float f32x2;

__device__ __forceinline__ short f2bs(float x) {
    union { float f; unsigned u; } v; v.f = x;
    unsigned rr = (v.u + 0x7fffu + ((v.u >> 16) & 1u)) >> 16;  // RNE
    return (short)(rr & 0xffffu);
}

__device__ __forceinline__ float bs2f_lo(int p) {
    union { unsigned u; float f; } v; v.u = (unsigned)p << 16; return v.f;
}
__device__ __forceinline__ float bs2f_hi(int p) {
    union { unsigned u; float f; } v; v.u = (unsigned)p & 0xffff0000u; return v.f;
}

__device__ __forceinline__ int rel_of(long e) {
    return (e >= 2L * EE) ? 2 : ((e >= (long)EE) ? 1 : 0);
}

__device__ __forceinline__ float ftanh(float x) {   // overflow-safe fast tanh
    float a = __expf(2.0f * fabsf(x));
    return copysignf(1.0f - 2.0f / (a + 1.0f), x);
}

// --- merged prep: blocks [0,NEBLK) do edge bucket-count; rest do feat conversion ---
__global__ __launch_bounds__(256)
void prep_kernel(const float* __restrict__ feat, short* __restrict__ featb,
                 int* __restrict__ featq,
                 const int* __restrict__ dst, int* __restrict__ bcnt) {
    if (blockIdx.x < NEBLK) {
        __shared__ int hist[NBK];
        for (int i = threadIdx.x; i < NBK; i += 256) hist[i] = 0;
        __syncthreads();
        long ebase = (long)blockIdx.x * ECHUNK;
        for (int i = threadIdx.x; i < ECHUNK; i += 256) {
            long e = ebase + i;
            if (e < RE)
                atomicAdd(&hist[rel_of(e) * NTPR + (dst[e] >> 7)], 1);
        }
        __syncthreads();
        for (int i = threadIdx.x; i < NBK; i += 256) {
            int v = hist[i];
            if (v) atomicAdd(&bcnt[i], v);   // no-return, spread
        }
    } else {
        int gid = (blockIdx.x - NEBLK) * 256 + threadIdx.x;   // 8 elems per thread
        if (gid >= NN * 16) return;
        f32x4 a = ((const f32x4*)feat)[2 * gid];
        f32x4 b = ((const f32x4*)feat)[2 * gid + 1];
        bf16x8 o;
        o[0] = f2bs(a.x); o[1] = f2bs(a.y); o[2] = f2bs(a.z); o[3] = f2bs(a.w);
        o[4] = f2bs(b.x); o[5] = f2bs(b.y); o[6] = f2bs(b.z); o[7] = f2bs(b.w);
        ((bf16x8*)featb)[gid] = o;
        int lo = 0, hi = 0;
        lo = __builtin_amdgcn_cvt_pk_fp8_f32(a.x, a.y, lo, false);
        lo = __builtin_amdgcn_cvt_pk_fp8_f32(a.z, a.w, lo, true);
        hi = __builtin_amdgcn_cvt_pk_fp8_f32(b.x, b.y, hi, false);
        hi = __builtin_amdgcn_cvt_pk_fp8_f32(b.z, b.w, hi, true);
        int2 pk; pk.x = lo; pk.y = hi;
        ((int2*)featq)[gid] = pk;
    }
}

// ---------------- bucket scan (1173 buckets, single block) ----------------
__global__ __launch_bounds__(256)
void bscan_kernel(const int* __restrict__ bcnt, int* __restrict__ bstart,
                  int* __restrict__ boff) {
    __shared__ int sm[256];
    int t = threadIdx.x;
    int loc[5];
    int s = 0;
    #pragma unroll
    for (int i = 0; i < 5; ++i) {
        int idx = t * 5 + i;
        int v = (idx < NBK) ? bcnt[idx] : 0;
        loc[i] = v; s += v;
    }
    sm[t] = s;
    __syncthreads();
    for (int d = 1; d < 256; d <<= 1) {
        int u = (t >= d) ? sm[t - d] : 0;
        __syncthreads();
        sm[t] += u;
        __syncthreads();
    }
    int run = sm[t] - s;   // exclusive prefix
    #pragma unroll
    for (int i = 0; i < 5; ++i) {
        int idx = t * 5 + i;
        if (idx < NBK) { bstart[idx] = run; boff[idx] = run; run += loc[i]; }
    }
}

// ------- phase A: block-aggregated bucket scatter (LDS hist + range reservation) -------
__global__ __launch_bounds__(256)
void bscatterA(const int* __restrict__ src, const int* __restrict__ dst,
               int* __restrict__ boff, unsigned* __restrict__ bpair) {
    __shared__ int hist[NBK];
    __shared__ int base[NBK];
    for (int i = threadIdx.x; i < NBK; i += 256) hist[i] = 0;
    __syncthreads();
    long ebase = (long)blockIdx.x * ECHUNK;
    for (int i = threadIdx.x; i < ECHUNK; i += 256) {
        long e = ebase + i;
        if (e < RE)
            atomicAdd(&hist[rel_of(e) * NTPR + (dst[e] >> 7)], 1);
    }
    __syncthreads();
    for (int i = threadIdx.x; i < NBK; i += 256) {
        int v = hist[i];
        base[i] = v ? atomicAdd(&boff[i], v) : 0;   // one reservation per (block,bucket)
    }
    __syncthreads();
    for (int i = threadIdx.x; i < ECHUNK; i += 256) {
        long e = ebase + i;
        if (e < RE) {
            int r = rel_of(e);
            int d = dst[e];
            int b = r * NTPR + (d >> 7);
            int pos = atomicAdd(&base[b], 1);       // LDS cursor bump
            bpair[pos] = ((unsigned)(d & 127) << 16) | (unsigned)src[e];
        }
    }
}

// ------- phase B: per-bucket scatter + derive per-node cnt/off (no global scan) -------
__global__ __launch_bounds__(256)
void scatterB(const unsigned* __restrict__ bpair, const int* __restrict__ bstart,
              const int* __restrict__ bcnt,
              int* __restrict__ off, int* __restrict__ cnt,
              int* __restrict__ csr) {
    __shared__ int hist[128];    // per-node count within bucket
    __shared__ int pre[128];     // inclusive prefix
    __shared__ int base[128];    // global start offset per node
    int b = blockIdx.x;
    int r = b / NTPR, tile = b - r * NTPR;
    const int t = threadIdx.x;
    if (t < 128) hist[t] = 0;
    __syncthreads();
    int start = bstart[b], end = start + bcnt[b];
    for (int i = start + t; i < end; i += 256)
        atomicAdd(&hist[bpair[i] >> 16], 1);
    __syncthreads();
    if (t < 128) pre[t] = hist[t];
    __syncthreads();
    for (int d = 1; d < 128; d <<= 1) {
        int v = (t < 128 && t >= d) ? pre[t - d] : 0;
        __syncthreads();
        if (t < 128) pre[t] += v;
        __syncthreads();
    }
    if (t < 128) {
        int excl = pre[t] - hist[t];
        base[t] = start + excl;
        int nloc = tile * 128 + t;
        if (nloc < NN) {
            off[r * NN + nloc] = start + excl;    // coalesced
            cnt[r * NN + nloc] = hist[t];         // coalesced
        }
        hist[t] = 0;                              // reuse as placement cursor
    }
    __syncthreads();
    for (int i = start + t; i < end; i += 256) {
        unsigned p = bpair[i];
        int d = (int)(p >> 16);
        int rank = atomicAdd(&hist[d], 1);        // LDS only
        csr[base[d] + rank] = (int)(p & 0xFFFFu);
    }
}

// --- aggregation: wave per (r,node), int4 csr + fp8 rows + packed f32x2 accum ---
__global__ __launch_bounds__(256)
void gather_kernel(const short* __restrict__ featb,
                   const int* __restrict__ featq,
                   const int* __restrict__ csr,
                   const int* __restrict__ off,   // START offsets (never mutated)
                   const int* __restrict__ cnt,
                   short* __restrict__ ssumb) {   // [R][N][F] <- bf16(feat + mean)
    int gid = blockIdx.x * blockDim.x + threadIdx.x;
    int w = gid >> 6, lane = gid & 63;
    if (w >= RN) return;
    int c = cnt[w];
    int start = off[w];
    int end = start + c;
    const unsigned short* q = (const unsigned short*)featq;   // 2 fp8 per ushort
    f32x2 a0 = {0.f, 0.f}, a1 = {0.f, 0.f}, a2 = {0.f, 0.f}, a3 = {0.f, 0.f};
    f32x2 a4 = {0.f, 0.f}, a5 = {0.f, 0.f}, a6 = {0.f, 0.f}, a7 = {0.f, 0.f};
    int j = start;
    // scalar prologue: align j to a multiple of 4 for int4 csr loads
    int pre = (start + 3) & ~3;
    if (pre > end) pre = end;
    for (; j < pre; ++j) {
        int v = q[(size_t)csr[j] * 64 + lane];
        a0 += __builtin_amdgcn_cvt_pk_f32_fp8(v, false);
    }
    for (; j + 7 < end; j += 8) {
        int4 ca = *(const int4*)&csr[j];
        int4 cb = *(const int4*)&csr[j + 4];
        int v0 = q[(size_t)ca.x * 64 + lane];
        int v1 = q[(size_t)ca.y * 64 + lane];
        int v2 = q[(size_t)ca.z * 64 + lane];
        int v3 = q[(size_t)ca.w * 64 + lane];
        int v4 = q[(size_t)cb.x * 64 + lane];
        int v5 = q[(size_t)cb.y * 64 + lane];
        int v6 = q[(size_t)cb.z * 64 + lane];
        int v7 = q[(size_t)cb.w * 64 + lane];
        a0 += __builtin_amdgcn_cvt_pk_f32_fp8(v0, false);
        a1 += __builtin_amdgcn_cvt_pk_f32_fp8(v1, false);
        a2 += __builtin_amdgcn_cvt_pk_f32_fp8(v2, false);
        a3 += __builtin_amdgcn_cvt_pk_f32_fp8(v3, false);
        a4 += __builtin_amdgcn_cvt_pk_f32_fp8(v4, false);
        a5 += __builtin_amdgcn_cvt_pk_f32_fp8(v5, false);
        a6 += __builtin_amdgcn_cvt_pk_f32_fp8(v6, false);
        a7 += __builtin_amdgcn_cvt_pk_f32_fp8(v7, false);
    }
    if (j + 3 < end) {
        int4 ca = *(const int4*)&csr[j];
        int v0 = q[(size_t)ca.x * 64 + lane];
        int v1 = q[(size_t)ca.y * 64 + lane];
        int v2 = q[(size_t)ca.z * 64 + lane];
        int v3 = q[(size_t)ca.w * 64 + lane];
        a0 += __builtin_amdgcn_cvt_pk_f32_fp8(v0, false);
        a1 += __builtin_amdgcn_cvt_pk_f32_fp8(v1, false);
        a2 += __builtin_amdgcn_cvt_pk_f32_fp8(v2, false);
        a3 += __builtin_amdgcn_cvt_pk_f32_fp8(v3, false);
        j += 4;
    }
    for (; j < end; ++j) {
        int v = q[(size_t)csr[j] * 64 + lane];
        a0 += __builtin_amdgcn_cvt_pk_f32_fp8(v, false);
    }
    f32x2 a = ((a0 + a1) + (a2 + a3)) + ((a4 + a5) + (a6 + a7));
    float inv = 1.0f / fmaxf((float)c, 1.0f);
    int n = w % NN;
    int fv = ((const int*)featb)[(size_t)n * 64 + lane];   // exact bf16 residual
    float hx = bs2f_lo(fv) + a[0] * inv;
    float hy = bs2f_hi(fv) + a[1] * inv;
    unsigned plo = (unsigned short)f2bs(hx);
    unsigned phi = (unsigned short)f2bs(hy);
    ((int*)ssumb)[(size_t)w * 64 + lane] = (int)((phi << 16) | plo);
}

// ======= split MFMA transform: 512-thr blocks, 8 waves, 16-node tile/wave =======

__device__ __forceinline__ void mfma_layer(const bf16x8 A[4], const short* Wlds,
                                           int g8, int c, f32x4 acc[8]) {
    #pragma unroll
    for (int kk = 0; kk < 4; ++kk) {
        #pragma unroll
        for (int t = 0; t < 8; ++t) {
            int d = t * 16 + c;
            bf16x8 B = *(const bf16x8*)&Wlds[d * 128 + ((kk * 32 + g8) ^ ((d & 7) << 3))];
            acc[t] = __builtin_amdgcn_mfma_f32_16x16x32_bf16(A[kk], B, acc[t], 0, 0, 0);
        }
    }
}

template <bool RELU, bool BIAS>
__device__ __forceinline__ void ln_block(f32x4 acc[8], const float* bias,
                                         const float* gam, const float* bet, int c) {
    float s0 = 0, s1 = 0, s2 = 0, s3 = 0, p0 = 0, p1 = 0, p2 = 0, p3 = 0;
    #pragma unroll
    for (int t = 0; t < 8; ++t) {
        if (BIAS) {
            float bb = bias[t * 16 + c];
            acc[t][0] += bb; acc[t][1] += bb;
            acc[t][2] += bb; acc[t][3] += bb;
        }
        s0 += acc[t][0]; p0 += acc[t][0] * acc[t][0];
        s1 += acc[t][1]; p1 += acc[t][1] * acc[t][1];
        s2 += acc[t][2]; p2 += acc[t][2] * acc[t][2];
        s3 += acc[t][3]; p3 += acc[t][3] * acc[t][3];
    }
    #pragma unroll
    for (int m = 1; m < 16; m <<= 1) {
        s0 += __shfl_xor(s0, m); s1 += __shfl_xor(s1, m);
        s2 += __shfl_xor(s2, m); s3 += __shfl_xor(s3, m);
        p0 += __shfl_xor(p0, m); p1 += __shfl_xor(p1, m);
        p2 += __shfl_xor(p2, m); p3 += __shfl_xor(p3, m);
    }
    const float inv = 1.0f / 128.0f;
    float mu0 = s0 * inv, mu1 = s1 * inv, mu2 = s2 * inv, mu3 = s3 * inv;
    float r0 = rsqrtf(p0 * inv - mu0 * mu0 + EPSF);
    float r1 = rsqrtf(p1 * inv - mu1 * mu1 + EPSF);
    float r2 = rsqrtf(p2 * inv - mu2 * mu2 + EPSF);
    float r3 = rsqrtf(p3 * inv - mu3 * mu3 + EPSF);
    #pragma unroll
    for (int t = 0; t < 8; ++t) {
        float gg = gam[t * 16 + c], bb = bet[t * 16 + c];
        float v0 = (acc[t][0] - mu0) * r0 * gg + bb;
        float v1 = (acc[t][1] - mu1) * r1 * gg + bb;
        float v2 = (acc[t][2] - mu2) * r2 * gg + bb;
        float v3 = (acc[t][3] - mu3) * r3 * gg + bb;
        if (RELU) {
            v0 = fmaxf(v0, 0.f); v1 = fmaxf(v1, 0.f);
            v2 = fmaxf(v2, 0.f); v3 = fmaxf(v3, 0.f);
        }
        acc[t][0] = v0; acc[t][1] = v1;
        acc[t][2] = v2; acc[t][3] = v3;
    }
}

__device__ __forceinline__ void store_ht(const f32x4 acc[8], short* myht, int g, int c) {
    #pragma unroll
    for (int t = 0; t < 8; ++t) {
        int col = t * 16 + c;
        #pragma unroll
        for (int qq = 0; qq < 4; ++qq) {
            int row = g * 4 + qq;
            myht[row * 128 + (col ^ ((row & 7) << 3))] = f2bs(acc[t][qq]);
        }
    }
}

__device__ __forceinline__ void ht_to_global(const short* myht, short* gout, int g, int c) {
    #pragma unroll
    for (int cc = 0; cc < 4; ++cc) {
        int row = cc * 4 + g;
        int col0 = c * 8;
        bf16x8 v = *(const bf16x8*)&myht[row * 128 + (col0 ^ ((row & 7) << 3))];
        *(bf16x8*)&gout[row * FF + col0] = v;
    }
}

// layer 1: X1 = relu(LN(h @ W0 + b0)), in-place over hbuf
__global__ __launch_bounds__(512)
void fused_l1(short* hbuf,
              const float* __restrict__ W0, const float* __restrict__ b0,
              const float* __restrict__ ln_g, const float* __restrict__ ln_b) {
    __shared__ short W0t[FF * DD];        // 32 KiB
    __shared__ short ht[8][16 * DD];      // 32 KiB
    __shared__ float b0s[DD], lgs[DD], lbs[DD];

    const int r = blockIdx.y;
    const int tid = threadIdx.x;

    for (int i = tid; i < FF * DD; i += 512) {
        int k = i >> 7, d = i & 127;
        W0t[d * 128 + (k ^ ((d & 7) << 3))] = f2bs(W0[(size_t)r * FF * DD + i]);
    }
    if (tid < DD) {
        b0s[tid] = b0[r * DD + tid];
        lgs[tid] = ln_g[r * DD + tid];
        lbs[tid] = ln_b[r * DD + tid];
    }
    __syncthreads();

    const int wv = tid >> 6, ln = tid & 63;
    const int g = ln >> 4, c = ln & 15;
    const int g8 = g * 8;
    short* myht = ht[wv];

    for (int tile = blockIdx.x * 8 + wv; tile < NTILES; tile += gridDim.x * 8) {
        const int nbase = tile * 16;
        bf16x8 A[4];
        {
            const short* sp = hbuf + ((size_t)r * NN + nbase + c) * FF;
            #pragma unroll
            for (int kk = 0; kk < 4; ++kk)
                A[kk] = *(const bf16x8*)(sp + kk * 32 + g8);
        }
        f32x4 acc[8];
        #pragma unroll
        for (int t = 0; t < 8; ++t) acc[t] = (f32x4){0.f, 0.f, 0.f, 0.f};
        mfma_layer(A, W0t, g8, c, acc);
        ln_block<true, true>(acc, b0s, lgs, lbs, c);
        store_ht(acc, myht, g, c);
        ht_to_global(myht, hbuf + ((size_t)r * NN + nbase) * FF, g, c);
    }
}

// layer 2 + final LN: h = LN(relu(LN(X1 @ W1 + b1))), in-place over hbuf
__global__ __launch_bounds__(512)
void fused_l2(short* hbuf,
              const float* __restrict__ W1, const float* __restrict__ b1,
              const float* __restrict__ ln_g, const float* __restrict__ ln_b,
              const float* __restrict__ LN_g, const float* __restrict__ LN_b) {
    __shared__ short W1t[DD * DD];        // 32 KiB
    __shared__ short ht[8][16 * DD];      // 32 KiB
    __shared__ float b1s[DD], lgs[DD], lbs[DD], Lgs[DD], Lbs[DD];

    const int r = blockIdx.y;
    const int tid = threadIdx.x;

    for (int i = tid; i < DD * DD; i += 512) {
        int k = i >> 7, d = i & 127;
        W1t[d * 128 + (k ^ ((d & 7) << 3))] = f2bs(W1[(size_t)r * DD * DD + i]);
    }
    if (tid < DD) {
        b1s[tid] = b1[r * DD + tid];
        lgs[tid] = ln_g[r * DD + tid];
        lbs[tid] = ln_b[r * DD + tid];
        Lgs[tid] = LN_g[tid];
        Lbs[tid] = LN_b[tid];
    }
    __syncthreads();

    const int wv = tid >> 6, ln = tid & 63;
    const int g = ln >> 4, c = ln & 15;
    const int g8 = g * 8;
    short* myht = ht[wv];

    for (int tile = blockIdx.x * 8 + wv; tile < NTILES; tile += gridDim.x * 8) {
        const int nbase = tile * 16;
        bf16x8 A[4];
        {
            const short* sp = hbuf + ((size_t)r * NN + nbase + c) * FF;
            #pragma unroll
            for (int kk = 0; kk < 4; ++kk)
                A[kk] = *(const bf16x8*)(sp + kk * 32 + g8);
        }
        f32x4 acc[8];
        #pragma unroll
        for (int t = 0; t < 8; ++t) acc[t] = (f32x4){0.f, 0.f, 0.f, 0.f};
        mfma_layer(A, W1t, g8, c, acc);
        ln_block<true, true>(acc, b1s, lgs, lbs, c);
        ln_block<false, false>(acc, nullptr, Lgs, Lbs, c);
        store_ht(acc, myht, g, c);
        ht_to_global(myht, hbuf + ((size_t)r * NN + nbase) * FF, g, c);
    }
}

// ------ fused attention + softmax + combine: wave per 16-node tile, all 3 relations ------
__global__ __launch_bounds__(256)
void attn_combine(const short* __restrict__ hbuf,
                  const float* __restrict__ Wa1, const float* __restrict__ Wa2,
                  float* __restrict__ out) {
    __shared__ short Wa1t[RR][AA * DD];   // 48 KiB, [r][a][k] swizzled
    __shared__ float wa2s[RR][AA];

    const int tid = threadIdx.x;
    for (int i = tid; i < RR * DD * AA; i += 256) {
        int r2 = i >> 13;                  // / 8192
        int rem = i & 8191;
        int k = rem >> 6, a = rem & 63;
        Wa1t[r2][a * 128 + (k ^ ((a & 7) << 3))] = f2bs(Wa1[i]);
    }
    if (tid < RR * AA) wa2s[tid >> 6][tid & 63] = Wa2[tid];
    __syncthreads();

    const int wv = tid >> 6, ln = tid & 63;
    const int col = ln & 15, g = ln >> 4;
    const int g8 = g * 8, g4 = g * 4;

    for (int tile = blockIdx.x * 4 + wv; tile < NTILES; tile += gridDim.x * 4) {
        const int nbase = tile * 16;
        bf16x8 Bh[RR][4];
        float e[RR];
        #pragma unroll
        for (int r = 0; r < RR; ++r) {
            const short* hrow = hbuf + ((size_t)r * NN + nbase + col) * FF;
            #pragma unroll
            for (int kk = 0; kk < 4; ++kk)
                Bh[r][kk] = *(const bf16x8*)(hrow + kk * 32 + g8);
            f32x4 acc[4];
            #pragma unroll
            for (int t = 0; t < 4; ++t) acc[t] = (f32x4){0.f, 0.f, 0.f, 0.f};
            #pragma unroll
            for (int kk = 0; kk < 4; ++kk)
                #pragma unroll
                for (int t = 0; t < 4; ++t) {
                    int a_ = t * 16 + col;
                    bf16x8 Wf = *(const bf16x8*)&Wa1t[r][a_ * 128 + ((kk * 32 + g8) ^ ((a_ & 7) << 3))];
                    acc[t] = __builtin_amdgcn_mfma_f32_16x16x32_bf16(Wf, Bh[r][kk], acc[t], 0, 0, 0);
                }
            float ee = 0.f;
            #pragma unroll
            for (int t = 0; t < 4; ++t) {
                f32x4 wv2 = *(const f32x4*)&wa2s[r][t * 16 + g4];
                ee += ftanh(acc[t][0]) * wv2[0] + ftanh(acc[t][1]) * wv2[1]
                    + ftanh(acc[t][2]) * wv2[2] + ftanh(acc[t][3]) * wv2[3];
            }
            ee += __shfl_xor(ee, 16);
            ee += __shfl_xor(ee, 32);
            e[r] = ee;                      // identical across the 4 g-lanes of col
        }
        float m = fmaxf(e[0], fmaxf(e[1], e[2]));
        float w0 = __expf(e[0] - m), w1 = __expf(e[1] - m), w2 = __expf(e[2] - m);
        float inv = 1.0f / (w0 + w1 + w2);
        w0 *= inv; w1 *= inv; w2 *= inv;

        float* orow = out + (size_t)(nbase + col) * DD;
        #pragma unroll
        for (int kk = 0; kk < 4; ++kk) {
            union { bf16x8 v; int i[4]; } u0, u1, u2;
            u0.v = Bh[0][kk]; u1.v = Bh[1][kk]; u2.v = Bh[2][kk];
            f32x4 lo, hi;
            #pragma unroll
            for (int p = 0; p < 4; ++p) {
                float va = w0 * bs2f_lo(u0.i[p]) + w1 * bs2f_lo(u1.i[p]) + w2 * bs2f_lo(u2.i[p]);
                float vb = w0 * bs2f_hi(u0.i[p]) + w1 * bs2f_hi(u1.i[p]) + w2 * bs2f_hi(u2.i[p]);
                if (p < 2) { lo[2 * p] = va; lo[2 * p + 1] = vb; }
                else       { hi[2 * (p - 2)] = va; hi[2 * (p - 2) + 1] = vb; }
            }
            *(f32x4*)(orow + kk * 32 + g8) = lo;
            *(f32x4*)(orow + kk * 32 + g8 + 4) = hi;
        }
    }
}

extern "C" void kernel_launch(void* const* d_in, const int* in_sizes, int n_in,
                              void* d_out, int out_size, void* d_ws, size_t ws_size,
                              hipStream_t stream) {
    const float* feat = (const float*)d_in[0];
    const int*   src  = (const int*)d_in[1];
    const int*   dst  = (const int*)d_in[2];
    const float* W0   = (const float*)d_in[3];
    const float* b0   = (const float*)d_in[4];
    const float* W1   = (const float*)d_in[5];
    const float* b1   = (const float*)d_in[6];
    const float* ln_g = (const float*)d_in[7];
    const float* ln_b = (const float*)d_in[8];
    const float* LN_g = (const float*)d_in[9];
    const float* LN_b = (const float*)d_in[10];
    const float* Wa1  = (const float*)d_in[11];
    const float* Wa2  = (const float*)d_in[12];
    float* out = (float*)d_out;

    // workspace layout
    short*    ssumb  = (short*)d_ws;                        // RN*FF bf16 (38.4 MB)
    short*    featb  = ssumb + (size_t)RN * FF;             // NN*FF bf16 (12.8 MB)
    int*      featq  = (int*)(featb + (size_t)NN * FF);     // NN*FF fp8 (6.4 MB)
    int*      cnt    = featq + (size_t)NN * 32;             // RN (written by scatterB)
    int*      off    = cnt + RN;                            // RN (written by scatterB)
    int*      csr    = off + RN;                            // RE
    int*      bcnt   = csr + RE;                            // NBK
    int*      bstart = bcnt + NBK;                          // NBK
    int*      boff   = bstart + NBK;                        // NBK
    unsigned* bpair  = (unsigned*)(boff + NBK);             // RE (9.6 MB)

    hipMemsetAsync(bcnt, 0, (size_t)NBK * sizeof(int), stream);
    prep_kernel<<<NEBLK + FBLK, 256, 0, stream>>>(feat, featb, featq, dst, bcnt);
    bscan_kernel<<<1, 256, 0, stream>>>(bcnt, bstart, boff);
    bscatterA<<<NEBLK, 256, 0, stream>>>(src, dst, boff, bpair);
    scatterB<<<NBK, 256, 0, stream>>>(bpair, bstart, bcnt, off, cnt, csr);
    gather_kernel<<<(RN * 64 + 255) / 256, 256, 0, stream>>>(featb, featq, csr, off, cnt, ssumb);

    const int GX = (NTILES + 7) / 8;                        // 391 blocks/relation
    fused_l1<<<dim3(GX, RR), 512, 0, stream>>>(ssumb, W0, b0, ln_g, ln_b);
    fused_l2<<<dim3(GX, RR), 512, 0, stream>>>(ssumb, W1, b1, ln_g, ln_b, LN_g, LN_b);
    attn_combine<<<(NTILES + 3) / 4, 256, 0, stream>>>(ssumb, Wa1, Wa2, out);
}

// Round 17
// 306.049 us; speedup vs baseline: 1.0657x; 1.0657x over previous
//
#include <hip/hip_runtime.h>

#define RR 3
#define NN 50000
#define EE 800000
#define FF 128
#define DD 128
#define AA 64
#define EPSF 1e-5f
#define RN (RR * NN)
#define RE (RR * EE)
#define NTPR ((NN + 127) / 128)     // 391 dst-tiles (128 nodes) per relation
#define NBK (RR * NTPR)             // 1173 buckets
#define ECHUNK 8192                 // edges per bucketing block
#define NEBLK ((RE + ECHUNK - 1) / ECHUNK)   // 293
#define NTILES (NN / 16)            // 3125 exact

typedef __attribute__((ext_vector_type(8))) short bf16x8;
typedef __attribute__((ext_vector_type(4))) float f32x4;
typedef __attribute__((ext_vector_type(2))) float f32x2;

__device__ __forceinline__ short f2bs(float x) {
    union { float f; unsigned u; } v; v.f = x;
    unsigned rr = (v.u + 0x7fffu + ((v.u >> 16) & 1u)) >> 16;  // RNE
    return (short)(rr & 0xffffu);
}

__device__ __forceinline__ float bs2f_lo(int p) {
    union { unsigned u; float f; } v; v.u = (unsigned)p << 16; return v.f;
}
__device__ __forceinline__ float bs2f_hi(int p) {
    union { unsigned u; float f; } v; v.u = (unsigned)p & 0xffff0000u; return v.f;
}

__device__ __forceinline__ int rel_of(long e) {
    return (e >= 2L * EE) ? 2 : ((e >= (long)EE) ? 1 : 0);
}

__device__ __forceinline__ float ftanh(float x) {   // overflow-safe fast tanh
    float a = __expf(2.0f * fabsf(x));
    return copysignf(1.0f - 2.0f / (a + 1.0f), x);
}

// ---------------- feat -> bf16 table + fp8(e4m3, HW RNE) neighbor table ----------------
__global__ __launch_bounds__(256)
void feat2both(const float* __restrict__ feat, short* __restrict__ featb,
               int* __restrict__ featq) {
    int gid = blockIdx.x * blockDim.x + threadIdx.x;   // 8 elems per thread
    if (gid >= NN * 16) return;
    f32x4 a = ((const f32x4*)feat)[2 * gid];
    f32x4 b = ((const f32x4*)feat)[2 * gid + 1];
    bf16x8 o;
    o[0] = f2bs(a.x); o[1] = f2bs(a.y); o[2] = f2bs(a.z); o[3] = f2bs(a.w);
    o[4] = f2bs(b.x); o[5] = f2bs(b.y); o[6] = f2bs(b.z); o[7] = f2bs(b.w);
    ((bf16x8*)featb)[gid] = o;
    int lo = 0, hi = 0;
    lo = __builtin_amdgcn_cvt_pk_fp8_f32(a.x, a.y, lo, false);
    lo = __builtin_amdgcn_cvt_pk_fp8_f32(a.z, a.w, lo, true);
    hi = __builtin_amdgcn_cvt_pk_fp8_f32(b.x, b.y, hi, false);
    hi = __builtin_amdgcn_cvt_pk_fp8_f32(b.z, b.w, hi, true);
    int2 pk; pk.x = lo; pk.y = hi;
    ((int2*)featq)[gid] = pk;
}

// ------- count: bucket histogram only (LDS-aggregated, no per-node atomics) -------
__global__ __launch_bounds__(256)
void count_kernel(const int* __restrict__ dst, int* __restrict__ bcnt) {
    __shared__ int hist[NBK];
    for (int i = threadIdx.x; i < NBK; i += 256) hist[i] = 0;
    __syncthreads();
    long ebase = (long)blockIdx.x * ECHUNK;
    for (int i = threadIdx.x; i < ECHUNK; i += 256) {
        long e = ebase + i;
        if (e < RE)
            atomicAdd(&hist[rel_of(e) * NTPR + (dst[e] >> 7)], 1);
    }
    __syncthreads();
    for (int i = threadIdx.x; i < NBK; i += 256) {
        int v = hist[i];
        if (v) atomicAdd(&bcnt[i], v);   // no-return, spread
    }
}

// ---------------- bucket scan (1173 buckets, single block) ----------------
__global__ __launch_bounds__(256)
void bscan_kernel(const int* __restrict__ bcnt, int* __restrict__ bstart,
                  int* __restrict__ boff) {
    __shared__ int sm[256];
    int t = threadIdx.x;
    int loc[5];
    int s = 0;
    #pragma unroll
    for (int i = 0; i < 5; ++i) {
        int idx = t * 5 + i;
        int v = (idx < NBK) ? bcnt[idx] : 0;
        loc[i] = v; s += v;
    }
    sm[t] = s;
    __syncthreads();
    for (int d = 1; d < 256; d <<= 1) {
        int u = (t >= d) ? sm[t - d] : 0;
        __syncthreads();
        sm[t] += u;
        __syncthreads();
    }
    int run = sm[t] - s;   // exclusive prefix
    #pragma unroll
    for (int i = 0; i < 5; ++i) {
        int idx = t * 5 + i;
        if (idx < NBK) { bstart[idx] = run; boff[idx] = run; run += loc[i]; }
    }
}

// ------- phase A: block-aggregated bucket scatter (LDS hist + range reservation) -------
__global__ __launch_bounds__(256)
void bscatterA(const int* __restrict__ src, const int* __restrict__ dst,
               int* __restrict__ boff, unsigned* __restrict__ bpair) {
    __shared__ int hist[NBK];
    __shared__ int base[NBK];
    for (int i = threadIdx.x; i < NBK; i += 256) hist[i] = 0;
    __syncthreads();
    long ebase = (long)blockIdx.x * ECHUNK;
    for (int i = threadIdx.x; i < ECHUNK; i += 256) {
        long e = ebase + i;
        if (e < RE)
            atomicAdd(&hist[rel_of(e) * NTPR + (dst[e] >> 7)], 1);
    }
    __syncthreads();
    for (int i = threadIdx.x; i < NBK; i += 256) {
        int v = hist[i];
        base[i] = v ? atomicAdd(&boff[i], v) : 0;   // one reservation per (block,bucket)
    }
    __syncthreads();
    for (int i = threadIdx.x; i < ECHUNK; i += 256) {
        long e = ebase + i;
        if (e < RE) {
            int r = rel_of(e);
            int d = dst[e];
            int b = r * NTPR + (d >> 7);
            int pos = atomicAdd(&base[b], 1);       // LDS cursor bump
            bpair[pos] = ((unsigned)(d & 127) << 16) | (unsigned)src[e];
        }
    }
}

// ------- phase B: per-bucket scatter + derive per-node cnt/off (no global scan) -------
__global__ __launch_bounds__(256)
void scatterB(const unsigned* __restrict__ bpair, const int* __restrict__ bstart,
              const int* __restrict__ bcnt,
              int* __restrict__ off, int* __restrict__ cnt,
              int* __restrict__ csr) {
    __shared__ int hist[128];    // per-node count within bucket
    __shared__ int pre[128];     // inclusive prefix
    __shared__ int base[128];    // global start offset per node
    int b = blockIdx.x;
    int r = b / NTPR, tile = b - r * NTPR;
    const int t = threadIdx.x;
    if (t < 128) hist[t] = 0;
    __syncthreads();
    int start = bstart[b], end = start + bcnt[b];
    for (int i = start + t; i < end; i += 256)
        atomicAdd(&hist[bpair[i] >> 16], 1);
    __syncthreads();
    if (t < 128) pre[t] = hist[t];
    __syncthreads();
    for (int d = 1; d < 128; d <<= 1) {
        int v = (t < 128 && t >= d) ? pre[t - d] : 0;
        __syncthreads();
        if (t < 128) pre[t] += v;
        __syncthreads();
    }
    if (t < 128) {
        int excl = pre[t] - hist[t];
        base[t] = start + excl;
        int nloc = tile * 128 + t;
        if (nloc < NN) {
            off[r * NN + nloc] = start + excl;    // coalesced
            cnt[r * NN + nloc] = hist[t];         // coalesced
        }
        hist[t] = 0;                              // reuse as placement cursor
    }
    __syncthreads();
    for (int i = start + t; i < end; i += 256) {
        unsigned p = bpair[i];
        int d = (int)(p >> 16);
        int rank = atomicAdd(&hist[d], 1);        // LDS only
        csr[base[d] + rank] = (int)(p & 0xFFFFu);
    }
}

// --- aggregation: wave per (r,node), 8-way ILP, fp8 rows, scalar csr (R15 form) ---
__global__ __launch_bounds__(256)
void gather_kernel(const short* __restrict__ featb,
                   const int* __restrict__ featq,
                   const int* __restrict__ csr,
                   const int* __restrict__ off,   // START offsets (never mutated)
                   const int* __restrict__ cnt,
                   short* __restrict__ ssumb) {   // [R][N][F] <- bf16(feat + mean)
    int gid = blockIdx.x * blockDim.x + threadIdx.x;
    int w = gid >> 6, lane = gid & 63;
    if (w >= RN) return;
    int c = cnt[w];
    int start = off[w];
    int end = start + c;
    const unsigned short* q = (const unsigned short*)featq;   // 2 fp8 per ushort
    float ax0 = 0.f, ay0 = 0.f, ax1 = 0.f, ay1 = 0.f;
    float ax2 = 0.f, ay2 = 0.f, ax3 = 0.f, ay3 = 0.f;
    float ax4 = 0.f, ay4 = 0.f, ax5 = 0.f, ay5 = 0.f;
    float ax6 = 0.f, ay6 = 0.f, ax7 = 0.f, ay7 = 0.f;
    int j = start;
    for (; j + 7 < end; j += 8) {
        int s0 = csr[j + 0], s1 = csr[j + 1], s2 = csr[j + 2], s3 = csr[j + 3];
        int s4 = csr[j + 4], s5 = csr[j + 5], s6 = csr[j + 6], s7 = csr[j + 7];
        int v0 = q[(size_t)s0 * 64 + lane];
        int v1 = q[(size_t)s1 * 64 + lane];
        int v2 = q[(size_t)s2 * 64 + lane];
        int v3 = q[(size_t)s3 * 64 + lane];
        int v4 = q[(size_t)s4 * 64 + lane];
        int v5 = q[(size_t)s5 * 64 + lane];
        int v6 = q[(size_t)s6 * 64 + lane];
        int v7 = q[(size_t)s7 * 64 + lane];
        f32x2 f0 = __builtin_amdgcn_cvt_pk_f32_fp8(v0, false);
        f32x2 f1 = __builtin_amdgcn_cvt_pk_f32_fp8(v1, false);
        f32x2 f2v = __builtin_amdgcn_cvt_pk_f32_fp8(v2, false);
        f32x2 f3 = __builtin_amdgcn_cvt_pk_f32_fp8(v3, false);
        f32x2 f4 = __builtin_amdgcn_cvt_pk_f32_fp8(v4, false);
        f32x2 f5 = __builtin_amdgcn_cvt_pk_f32_fp8(v5, false);
        f32x2 f6 = __builtin_amdgcn_cvt_pk_f32_fp8(v6, false);
        f32x2 f7 = __builtin_amdgcn_cvt_pk_f32_fp8(v7, false);
        ax0 += f0[0]; ay0 += f0[1];
        ax1 += f1[0]; ay1 += f1[1];
        ax2 += f2v[0]; ay2 += f2v[1];
        ax3 += f3[0]; ay3 += f3[1];
        ax4 += f4[0]; ay4 += f4[1];
        ax5 += f5[0]; ay5 += f5[1];
        ax6 += f6[0]; ay6 += f6[1];
        ax7 += f7[0]; ay7 += f7[1];
    }
    for (; j + 3 < end; j += 4) {
        int s0 = csr[j + 0], s1 = csr[j + 1], s2 = csr[j + 2], s3 = csr[j + 3];
        int v0 = q[(size_t)s0 * 64 + lane];
        int v1 = q[(size_t)s1 * 64 + lane];
        int v2 = q[(size_t)s2 * 64 + lane];
        int v3 = q[(size_t)s3 * 64 + lane];
        f32x2 f0 = __builtin_amdgcn_cvt_pk_f32_fp8(v0, false);
        f32x2 f1 = __builtin_amdgcn_cvt_pk_f32_fp8(v1, false);
        f32x2 f2v = __builtin_amdgcn_cvt_pk_f32_fp8(v2, false);
        f32x2 f3 = __builtin_amdgcn_cvt_pk_f32_fp8(v3, false);
        ax0 += f0[0]; ay0 += f0[1];
        ax1 += f1[0]; ay1 += f1[1];
        ax2 += f2v[0]; ay2 += f2v[1];
        ax3 += f3[0]; ay3 += f3[1];
    }
    for (; j < end; ++j) {
        int s = csr[j];
        int v = q[(size_t)s * 64 + lane];
        f32x2 f0 = __builtin_amdgcn_cvt_pk_f32_fp8(v, false);
        ax0 += f0[0]; ay0 += f0[1];
    }
    float ax = ((ax0 + ax1) + (ax2 + ax3)) + ((ax4 + ax5) + (ax6 + ax7));
    float ay = ((ay0 + ay1) + (ay2 + ay3)) + ((ay4 + ay5) + (ay6 + ay7));
    float inv = 1.0f / fmaxf((float)c, 1.0f);
    int n = w % NN;
    int fv = ((const int*)featb)[(size_t)n * 64 + lane];   // exact bf16 residual
    float hx = bs2f_lo(fv) + ax * inv;
    float hy = bs2f_hi(fv) + ay * inv;
    unsigned plo = (unsigned short)f2bs(hx);
    unsigned phi = (unsigned short)f2bs(hy);
    ((int*)ssumb)[(size_t)w * 64 + lane] = (int)((phi << 16) | plo);
}

// ======= split MFMA transform: 512-thr blocks, 8 waves, 16-node tile/wave =======

__device__ __forceinline__ void mfma_layer(const bf16x8 A[4], const short* Wlds,
                                           int g8, int c, f32x4 acc[8]) {
    #pragma unroll
    for (int kk = 0; kk < 4; ++kk) {
        #pragma unroll
        for (int t = 0; t < 8; ++t) {
            int d = t * 16 + c;
            bf16x8 B = *(const bf16x8*)&Wlds[d * 128 + ((kk * 32 + g8) ^ ((d & 7) << 3))];
            acc[t] = __builtin_amdgcn_mfma_f32_16x16x32_bf16(A[kk], B, acc[t], 0, 0, 0);
        }
    }
}

template <bool RELU, bool BIAS>
__device__ __forceinline__ void ln_block(f32x4 acc[8], const float* bias,
                                         const float* gam, const float* bet, int c) {
    float s0 = 0, s1 = 0, s2 = 0, s3 = 0, p0 = 0, p1 = 0, p2 = 0, p3 = 0;
    #pragma unroll
    for (int t = 0; t < 8; ++t) {
        if (BIAS) {
            float bb = bias[t * 16 + c];
            acc[t][0] += bb; acc[t][1] += bb;
            acc[t][2] += bb; acc[t][3] += bb;
        }
        s0 += acc[t][0]; p0 += acc[t][0] * acc[t][0];
        s1 += acc[t][1]; p1 += acc[t][1] * acc[t][1];
        s2 += acc[t][2]; p2 += acc[t][2] * acc[t][2];
        s3 += acc[t][3]; p3 += acc[t][3] * acc[t][3];
    }
    #pragma unroll
    for (int m = 1; m < 16; m <<= 1) {
        s0 += __shfl_xor(s0, m); s1 += __shfl_xor(s1, m);
        s2 += __shfl_xor(s2, m); s3 += __shfl_xor(s3, m);
        p0 += __shfl_xor(p0, m); p1 += __shfl_xor(p1, m);
        p2 += __shfl_xor(p2, m); p3 += __shfl_xor(p3, m);
    }
    const float inv = 1.0f / 128.0f;
    float mu0 = s0 * inv, mu1 = s1 * inv, mu2 = s2 * inv, mu3 = s3 * inv;
    float r0 = rsqrtf(p0 * inv - mu0 * mu0 + EPSF);
    float r1 = rsqrtf(p1 * inv - mu1 * mu1 + EPSF);
    float r2 = rsqrtf(p2 * inv - mu2 * mu2 + EPSF);
    float r3 = rsqrtf(p3 * inv - mu3 * mu3 + EPSF);
    #pragma unroll
    for (int t = 0; t < 8; ++t) {
        float gg = gam[t * 16 + c], bb = bet[t * 16 + c];
        float v0 = (acc[t][0] - mu0) * r0 * gg + bb;
        float v1 = (acc[t][1] - mu1) * r1 * gg + bb;
        float v2 = (acc[t][2] - mu2) * r2 * gg + bb;
        float v3 = (acc[t][3] - mu3) * r3 * gg + bb;
        if (RELU) {
            v0 = fmaxf(v0, 0.f); v1 = fmaxf(v1, 0.f);
            v2 = fmaxf(v2, 0.f); v3 = fmaxf(v3, 0.f);
        }
        acc[t][0] = v0; acc[t][1] = v1;
        acc[t][2] = v2; acc[t][3] = v3;
    }
}

__device__ __forceinline__ void store_ht(const f32x4 acc[8], short* myht, int g, int c) {
    #pragma unroll
    for (int t = 0; t < 8; ++t) {
        int col = t * 16 + c;
        #pragma unroll
        for (int qq = 0; qq < 4; ++qq) {
            int row = g * 4 + qq;
            myht[row * 128 + (col ^ ((row & 7) << 3))] = f2bs(acc[t][qq]);
        }
    }
}

__device__ __forceinline__ void ht_to_global(const short* myht, short* gout, int g, int c) {
    #pragma unroll
    for (int cc = 0; cc < 4; ++cc) {
        int row = cc * 4 + g;
        int col0 = c * 8;
        bf16x8 v = *(const bf16x8*)&myht[row * 128 + (col0 ^ ((row & 7) << 3))];
        *(bf16x8*)&gout[row * FF + col0] = v;
    }
}

// layer 1: X1 = relu(LN(h @ W0 + b0)), in-place over hbuf
__global__ __launch_bounds__(512)
void fused_l1(short* hbuf,
              const float* __restrict__ W0, const float* __restrict__ b0,
              const float* __restrict__ ln_g, const float* __restrict__ ln_b) {
    __shared__ short W0t[FF * DD];        // 32 KiB
    __shared__ short ht[8][16 * DD];      // 32 KiB
    __shared__ float b0s[DD], lgs[DD], lbs[DD];

    const int r = blockIdx.y;
    const int tid = threadIdx.x;

    for (int i = tid; i < FF * DD; i += 512) {
        int k = i >> 7, d = i & 127;
        W0t[d * 128 + (k ^ ((d & 7) << 3))] = f2bs(W0[(size_t)r * FF * DD + i]);
    }
    if (tid < DD) {
        b0s[tid] = b0[r * DD + tid];
        lgs[tid] = ln_g[r * DD + tid];
        lbs[tid] = ln_b[r * DD + tid];
    }
    __syncthreads();

    const int wv = tid >> 6, ln = tid & 63;
    const int g = ln >> 4, c = ln & 15;
    const int g8 = g * 8;
    short* myht = ht[wv];

    for (int tile = blockIdx.x * 8 + wv; tile < NTILES; tile += gridDim.x * 8) {
        const int nbase = tile * 16;
        bf16x8 A[4];
        {
            const short* sp = hbuf + ((size_t)r * NN + nbase + c) * FF;
            #pragma unroll
            for (int kk = 0; kk < 4; ++kk)
                A[kk] = *(const bf16x8*)(sp + kk * 32 + g8);
        }
        f32x4 acc[8];
        #pragma unroll
        for (int t = 0; t < 8; ++t) acc[t] = (f32x4){0.f, 0.f, 0.f, 0.f};
        mfma_layer(A, W0t, g8, c, acc);
        ln_block<true, true>(acc, b0s, lgs, lbs, c);
        store_ht(acc, myht, g, c);
        ht_to_global(myht, hbuf + ((size_t)r * NN + nbase) * FF, g, c);
    }
}

// layer 2 + final LN: h = LN(relu(LN(X1 @ W1 + b1))), in-place over hbuf
__global__ __launch_bounds__(512)
void fused_l2(short* hbuf,
              const float* __restrict__ W1, const float* __restrict__ b1,
              const float* __restrict__ ln_g, const float* __restrict__ ln_b,
              const float* __restrict__ LN_g, const float* __restrict__ LN_b) {
    __shared__ short W1t[DD * DD];        // 32 KiB
    __shared__ short ht[8][16 * DD];      // 32 KiB
    __shared__ float b1s[DD], lgs[DD], lbs[DD], Lgs[DD], Lbs[DD];

    const int r = blockIdx.y;
    const int tid = threadIdx.x;

    for (int i = tid; i < DD * DD; i += 512) {
        int k = i >> 7, d = i & 127;
        W1t[d * 128 + (k ^ ((d & 7) << 3))] = f2bs(W1[(size_t)r * DD * DD + i]);
    }
    if (tid < DD) {
        b1s[tid] = b1[r * DD + tid];
        lgs[tid] = ln_g[r * DD + tid];
        lbs[tid] = ln_b[r * DD + tid];
        Lgs[tid] = LN_g[tid];
        Lbs[tid] = LN_b[tid];
    }
    __syncthreads();

    const int wv = tid >> 6, ln = tid & 63;
    const int g = ln >> 4, c = ln & 15;
    const int g8 = g * 8;
    short* myht = ht[wv];

    for (int tile = blockIdx.x * 8 + wv; tile < NTILES; tile += gridDim.x * 8) {
        const int nbase = tile * 16;
        bf16x8 A[4];
        {
            const short* sp = hbuf + ((size_t)r * NN + nbase + c) * FF;
            #pragma unroll
            for (int kk = 0; kk < 4; ++kk)
                A[kk] = *(const bf16x8*)(sp + kk * 32 + g8);
        }
        f32x4 acc[8];
        #pragma unroll
        for (int t = 0; t < 8; ++t) acc[t] = (f32x4){0.f, 0.f, 0.f, 0.f};
        mfma_layer(A, W1t, g8, c, acc);
        ln_block<true, true>(acc, b1s, lgs, lbs, c);
        ln_block<false, false>(acc, nullptr, Lgs, Lbs, c);
        store_ht(acc, myht, g, c);
        ht_to_global(myht, hbuf + ((size_t)r * NN + nbase) * FF, g, c);
    }
}

// ---------- attention scores: e = tanh(h @ Wa1) . Wa2 (transposed mfma) ----------
__global__ __launch_bounds__(256)
void attn_score(const short* __restrict__ hbuf,
                const float* __restrict__ Wa1, const float* __restrict__ Wa2,
                float* __restrict__ evec) {
    __shared__ short Wa1t[RR][AA * DD];   // 48 KiB, [r][a][k] swizzled
    __shared__ float wa2s[RR][AA];

    const int tid = threadIdx.x;
    for (int i = tid; i < RR * DD * AA; i += 256) {
        int r2 = i >> 13;                  // / 8192
        int rem = i & 8191;
        int k = rem >> 6, a = rem & 63;
        Wa1t[r2][a * 128 + (k ^ ((a & 7) << 3))] = f2bs(Wa1[i]);
    }
    if (tid < RR * AA) wa2s[tid >> 6][tid & 63] = Wa2[tid];
    __syncthreads();

    const int wv = tid >> 6, ln = tid & 63;
    const int col = ln & 15, g = ln >> 4;
    const int g8 = g * 8, g4 = g * 4;

    for (int idx = blockIdx.x * 4 + wv; idx < RR * NTILES; idx += gridDim.x * 4) {
        int r = idx / NTILES;
        int tile = idx - r * NTILES;
        int nbase = tile * 16;
        const short* hrow = hbuf + ((size_t)r * NN + nbase + col) * FF;

        f32x4 acc[4];
        #pragma unroll
        for (int t = 0; t < 4; ++t) acc[t] = (f32x4){0.f, 0.f, 0.f, 0.f};
        #pragma unroll
        for (int kk = 0; kk < 4; ++kk) {
            bf16x8 Bh = *(const bf16x8*)(hrow + kk * 32 + g8);
            #pragma unroll
            for (int t = 0; t < 4; ++t) {
                int a_ = t * 16 + col;
                bf16x8 Wf = *(const bf16x8*)&Wa1t[r][a_ * 128 + ((kk * 32 + g8) ^ ((a_ & 7) << 3))];
                acc[t] = __builtin_amdgcn_mfma_f32_16x16x32_bf16(Wf, Bh, acc[t], 0, 0, 0);
            }
        }
        float e = 0.f;
        #pragma unroll
        for (int t = 0; t < 4; ++t) {
            f32x4 wv2 = *(const f32x4*)&wa2s[r][t * 16 + g4];
            e += ftanh(acc[t][0]) * wv2[0] + ftanh(acc[t][1]) * wv2[1]
               + ftanh(acc[t][2]) * wv2[2] + ftanh(acc[t][3]) * wv2[3];
        }
        e += __shfl_xor(e, 16);
        e += __shfl_xor(e, 32);
        if (ln < 16) evec[(size_t)r * NN + nbase + ln] = e;
    }
}

// ---------------- softmax over relations + weighted combine ----------------
__global__ __launch_bounds__(256)
void combine_kernel(const short* __restrict__ hfb,
                    const float* __restrict__ evec,
                    float* __restrict__ out) {
    int gid = blockIdx.x * blockDim.x + threadIdx.x;
    if (gid >= NN * 64) return;
    int n = gid >> 6, j = gid & 63;
    float e0 = evec[n], e1 = evec[NN + n], e2 = evec[2 * NN + n];
    float m = fmaxf(e0, fmaxf(e1, e2));
    float w0 = __expf(e0 - m), w1 = __expf(e1 - m), w2 = __expf(e2 - m);
    float inv = 1.0f / (w0 + w1 + w2);
    w0 *= inv; w1 *= inv; w2 *= inv;
    const int* h0 = (const int*)hfb + (size_t)n * 64;
    const int* h1 = (const int*)hfb + ((size_t)NN + n) * 64;
    const int* h2 = (const int*)hfb + ((size_t)2 * NN + n) * 64;
    int a = h0[j], b = h1[j], d = h2[j];
    float2 o;
    o.x = w0 * bs2f_lo(a) + w1 * bs2f_lo(b) + w2 * bs2f_lo(d);
    o.y = w0 * bs2f_hi(a) + w1 * bs2f_hi(b) + w2 * bs2f_hi(d);
    ((float2*)out)[(size_t)n * 64 + j] = o;
}

extern "C" void kernel_launch(void* const* d_in, const int* in_sizes, int n_in,
                              void* d_out, int out_size, void* d_ws, size_t ws_size,
                              hipStream_t stream) {
    const float* feat = (const float*)d_in[0];
    const int*   src  = (const int*)d_in[1];
    const int*   dst  = (const int*)d_in[2];
    const float* W0   = (const float*)d_in[3];
    const float* b0   = (const float*)d_in[4];
    const float* W1   = (const float*)d_in[5];
    const float* b1   = (const float*)d_in[6];
    const float* ln_g = (const float*)d_in[7];
    const float* ln_b = (const float*)d_in[8];
    const float* LN_g = (const float*)d_in[9];
    const float* LN_b = (const float*)d_in[10];
    const float* Wa1  = (const float*)d_in[11];
    const float* Wa2  = (const float*)d_in[12];
    float* out = (float*)d_out;

    // workspace layout
    short*    ssumb  = (short*)d_ws;                        // RN*FF bf16 (38.4 MB)
    short*    featb  = ssumb + (size_t)RN * FF;             // NN*FF bf16 (12.8 MB)
    int*      featq  = (int*)(featb + (size_t)NN * FF);     // NN*FF fp8 (6.4 MB)
    int*      cnt    = featq + (size_t)NN * 32;             // RN (written by scatterB)
    int*      off    = cnt + RN;                            // RN (written by scatterB)
    int*      csr    = off + RN;                            // RE
    float*    evec   = (float*)(csr + RE);                  // RN
    int*      bcnt   = (int*)(evec + RN);                   // NBK
    int*      bstart = bcnt + NBK;                          // NBK
    int*      boff   = bstart + NBK;                        // NBK
    unsigned* bpair  = (unsigned*)(boff + NBK);             // RE (9.6 MB)

    feat2both<<<(NN * 16 + 255) / 256, 256, 0, stream>>>(feat, featb, featq);
    hipMemsetAsync(bcnt, 0, (size_t)NBK * sizeof(int), stream);
    count_kernel<<<NEBLK, 256, 0, stream>>>(dst, bcnt);
    bscan_kernel<<<1, 256, 0, stream>>>(bcnt, bstart, boff);
    bscatterA<<<NEBLK, 256, 0, stream>>>(src, dst, boff, bpair);
    scatterB<<<NBK, 256, 0, stream>>>(bpair, bstart, bcnt, off, cnt, csr);
    gather_kernel<<<(RN * 64 + 255) / 256, 256, 0, stream>>>(featb, featq, csr, off, cnt, ssumb);

    const int GX = (NTILES + 7) / 8;                        // 391 blocks/relation
    fused_l1<<<dim3(GX, RR), 512, 0, stream>>>(ssumb, W0, b0, ln_g, ln_b);
    fused_l2<<<dim3(GX, RR), 512, 0, stream>>>(ssumb, W1, b1, ln_g, ln_b, LN_g, LN_b);
    attn_score<<<512, 256, 0, stream>>>(ssumb, Wa1, Wa2, evec);
    combine_kernel<<<(NN * 64 + 255) / 256, 256, 0, stream>>>(ssumb, evec, out);
}

// Round 18
// 302.528 us; speedup vs baseline: 1.0781x; 1.0116x over previous
//
#include <hip/hip_runtime.h>

#define RR 3
#define NN 50000
#define EE 800000
#define FF 128
#define DD 128
#define AA 64
#define EPSF 1e-5f
#define RN (RR * NN)
#define RE (RR * EE)
#define NTPR ((NN + 127) / 128)     // 391 dst-tiles (128 nodes) per relation
#define NBK (RR * NTPR)             // 1173 buckets
#define ECHUNK 8192                 // edges per bucketing block
#define NEBLK ((RE + ECHUNK - 1) / ECHUNK)   // 293
#define NTILES (NN / 16)            // 3125 exact

typedef __attribute__((ext_vector_type(8))) short bf16x8;
typedef __attribute__((ext_vector_type(4))) float f32x4;
typedef __attribute__((ext_vector_type(2))) float f32x2;

__device__ __forceinline__ short f2bs(float x) {
    union { float f; unsigned u; } v; v.f = x;
    unsigned rr = (v.u + 0x7fffu + ((v.u >> 16) & 1u)) >> 16;  // RNE
    return (short)(rr & 0xffffu);
}

__device__ __forceinline__ float bs2f_lo(int p) {
    union { unsigned u; float f; } v; v.u = (unsigned)p << 16; return v.f;
}
__device__ __forceinline__ float bs2f_hi(int p) {
    union { unsigned u; float f; } v; v.u = (unsigned)p & 0xffff0000u; return v.f;
}

__device__ __forceinline__ int rel_of(long e) {
    return (e >= 2L * EE) ? 2 : ((e >= (long)EE) ? 1 : 0);
}

__device__ __forceinline__ float ftanh(float x) {   // overflow-safe fast tanh
    float a = __expf(2.0f * fabsf(x));
    return copysignf(1.0f - 2.0f / (a + 1.0f), x);
}

// ---------------- feat -> bf16 table + fp8(e4m3, HW RNE) neighbor table ----------------
__global__ __launch_bounds__(256)
void feat2both(const float* __restrict__ feat, short* __restrict__ featb,
               int* __restrict__ featq) {
    int gid = blockIdx.x * blockDim.x + threadIdx.x;   // 8 elems per thread
    if (gid >= NN * 16) return;
    f32x4 a = ((const f32x4*)feat)[2 * gid];
    f32x4 b = ((const f32x4*)feat)[2 * gid + 1];
    bf16x8 o;
    o[0] = f2bs(a.x); o[1] = f2bs(a.y); o[2] = f2bs(a.z); o[3] = f2bs(a.w);
    o[4] = f2bs(b.x); o[5] = f2bs(b.y); o[6] = f2bs(b.z); o[7] = f2bs(b.w);
    ((bf16x8*)featb)[gid] = o;
    int lo = 0, hi = 0;
    lo = __builtin_amdgcn_cvt_pk_fp8_f32(a.x, a.y, lo, false);
    lo = __builtin_amdgcn_cvt_pk_fp8_f32(a.z, a.w, lo, true);
    hi = __builtin_amdgcn_cvt_pk_fp8_f32(b.x, b.y, hi, false);
    hi = __builtin_amdgcn_cvt_pk_fp8_f32(b.z, b.w, hi, true);
    int2 pk; pk.x = lo; pk.y = hi;
    ((int2*)featq)[gid] = pk;
}

// ------- count: bucket histogram, persisted per-block for bscatterA reuse -------
__global__ __launch_bounds__(256)
void count_kernel(const int* __restrict__ dst, int* __restrict__ bcnt,
                  int* __restrict__ bhist) {
    __shared__ int hist[NBK];
    for (int i = threadIdx.x; i < NBK; i += 256) hist[i] = 0;
    __syncthreads();
    long ebase = (long)blockIdx.x * ECHUNK;
    for (int i = threadIdx.x; i < ECHUNK; i += 256) {
        long e = ebase + i;
        if (e < RE)
            atomicAdd(&hist[rel_of(e) * NTPR + (dst[e] >> 7)], 1);
    }
    __syncthreads();
    int* bh = bhist + (size_t)blockIdx.x * NBK;
    for (int i = threadIdx.x; i < NBK; i += 256) {
        int v = hist[i];
        bh[i] = v;                       // persist per-block histogram (coalesced)
        if (v) atomicAdd(&bcnt[i], v);   // no-return, spread
    }
}

// ---------------- bucket scan (1173 buckets, single block) ----------------
__global__ __launch_bounds__(256)
void bscan_kernel(const int* __restrict__ bcnt, int* __restrict__ bstart,
                  int* __restrict__ boff) {
    __shared__ int sm[256];
    int t = threadIdx.x;
    int loc[5];
    int s = 0;
    #pragma unroll
    for (int i = 0; i < 5; ++i) {
        int idx = t * 5 + i;
        int v = (idx < NBK) ? bcnt[idx] : 0;
        loc[i] = v; s += v;
    }
    sm[t] = s;
    __syncthreads();
    for (int d = 1; d < 256; d <<= 1) {
        int u = (t >= d) ? sm[t - d] : 0;
        __syncthreads();
        sm[t] += u;
        __syncthreads();
    }
    int run = sm[t] - s;   // exclusive prefix
    #pragma unroll
    for (int i = 0; i < 5; ++i) {
        int idx = t * 5 + i;
        if (idx < NBK) { bstart[idx] = run; boff[idx] = run; run += loc[i]; }
    }
}

// --- phase A: bucket scatter; per-block hist loaded from bhist (single edge pass) ---
__global__ __launch_bounds__(256)
void bscatterA(const int* __restrict__ src, const int* __restrict__ dst,
               const int* __restrict__ bhist,
               int* __restrict__ boff, unsigned* __restrict__ bpair) {
    __shared__ int base[NBK];
    const int* bh = bhist + (size_t)blockIdx.x * NBK;
    for (int i = threadIdx.x; i < NBK; i += 256) {
        int v = bh[i];
        base[i] = v ? atomicAdd(&boff[i], v) : 0;   // one reservation per (block,bucket)
    }
    __syncthreads();
    long ebase = (long)blockIdx.x * ECHUNK;
    for (int i = threadIdx.x; i < ECHUNK; i += 256) {
        long e = ebase + i;
        if (e < RE) {
            int r = rel_of(e);
            int d = dst[e];
            int b = r * NTPR + (d >> 7);
            int pos = atomicAdd(&base[b], 1);       // LDS cursor bump
            bpair[pos] = ((unsigned)(d & 127) << 16) | (unsigned)src[e];
        }
    }
}

// ------- phase B: per-bucket scatter + derive per-node cnt/off (no global scan) -------
__global__ __launch_bounds__(256)
void scatterB(const unsigned* __restrict__ bpair, const int* __restrict__ bstart,
              const int* __restrict__ bcnt,
              int* __restrict__ off, int* __restrict__ cnt,
              int* __restrict__ csr) {
    __shared__ int hist[128];    // per-node count within bucket
    __shared__ int pre[128];     // inclusive prefix
    __shared__ int base[128];    // global start offset per node
    int b = blockIdx.x;
    int r = b / NTPR, tile = b - r * NTPR;
    const int t = threadIdx.x;
    if (t < 128) hist[t] = 0;
    __syncthreads();
    int start = bstart[b], end = start + bcnt[b];
    for (int i = start + t; i < end; i += 256)
        atomicAdd(&hist[bpair[i] >> 16], 1);
    __syncthreads();
    if (t < 128) pre[t] = hist[t];
    __syncthreads();
    for (int d = 1; d < 128; d <<= 1) {
        int v = (t < 128 && t >= d) ? pre[t - d] : 0;
        __syncthreads();
        if (t < 128) pre[t] += v;
        __syncthreads();
    }
    if (t < 128) {
        int excl = pre[t] - hist[t];
        base[t] = start + excl;
        int nloc = tile * 128 + t;
        if (nloc < NN) {
            off[r * NN + nloc] = start + excl;    // coalesced
            cnt[r * NN + nloc] = hist[t];         // coalesced
        }
        hist[t] = 0;                              // reuse as placement cursor
    }
    __syncthreads();
    for (int i = start + t; i < end; i += 256) {
        unsigned p = bpair[i];
        int d = (int)(p >> 16);
        int rank = atomicAdd(&hist[d], 1);        // LDS only
        csr[base[d] + rank] = (int)(p & 0xFFFFu);
    }
}

// --- aggregation: wave per (r,node), 8-way ILP, fp8 rows, scalar csr (R15 form) ---
__global__ __launch_bounds__(256)
void gather_kernel(const short* __restrict__ featb,
                   const int* __restrict__ featq,
                   const int* __restrict__ csr,
                   const int* __restrict__ off,   // START offsets (never mutated)
                   const int* __restrict__ cnt,
                   short* __restrict__ ssumb) {   // [R][N][F] <- bf16(feat + mean)
    int gid = blockIdx.x * blockDim.x + threadIdx.x;
    int w = gid >> 6, lane = gid & 63;
    if (w >= RN) return;
    int c = cnt[w];
    int start = off[w];
    int end = start + c;
    const unsigned short* q = (const unsigned short*)featq;   // 2 fp8 per ushort
    float ax0 = 0.f, ay0 = 0.f, ax1 = 0.f, ay1 = 0.f;
    float ax2 = 0.f, ay2 = 0.f, ax3 = 0.f, ay3 = 0.f;
    float ax4 = 0.f, ay4 = 0.f, ax5 = 0.f, ay5 = 0.f;
    float ax6 = 0.f, ay6 = 0.f, ax7 = 0.f, ay7 = 0.f;
    int j = start;
    for (; j + 7 < end; j += 8) {
        int s0 = csr[j + 0], s1 = csr[j + 1], s2 = csr[j + 2], s3 = csr[j + 3];
        int s4 = csr[j + 4], s5 = csr[j + 5], s6 = csr[j + 6], s7 = csr[j + 7];
        int v0 = q[(size_t)s0 * 64 + lane];
        int v1 = q[(size_t)s1 * 64 + lane];
        int v2 = q[(size_t)s2 * 64 + lane];
        int v3 = q[(size_t)s3 * 64 + lane];
        int v4 = q[(size_t)s4 * 64 + lane];
        int v5 = q[(size_t)s5 * 64 + lane];
        int v6 = q[(size_t)s6 * 64 + lane];
        int v7 = q[(size_t)s7 * 64 + lane];
        f32x2 f0 = __builtin_amdgcn_cvt_pk_f32_fp8(v0, false);
        f32x2 f1 = __builtin_amdgcn_cvt_pk_f32_fp8(v1, false);
        f32x2 f2v = __builtin_amdgcn_cvt_pk_f32_fp8(v2, false);
        f32x2 f3 = __builtin_amdgcn_cvt_pk_f32_fp8(v3, false);
        f32x2 f4 = __builtin_amdgcn_cvt_pk_f32_fp8(v4, false);
        f32x2 f5 = __builtin_amdgcn_cvt_pk_f32_fp8(v5, false);
        f32x2 f6 = __builtin_amdgcn_cvt_pk_f32_fp8(v6, false);
        f32x2 f7 = __builtin_amdgcn_cvt_pk_f32_fp8(v7, false);
        ax0 += f0[0]; ay0 += f0[1];
        ax1 += f1[0]; ay1 += f1[1];
        ax2 += f2v[0]; ay2 += f2v[1];
        ax3 += f3[0]; ay3 += f3[1];
        ax4 += f4[0]; ay4 += f4[1];
        ax5 += f5[0]; ay5 += f5[1];
        ax6 += f6[0]; ay6 += f6[1];
        ax7 += f7[0]; ay7 += f7[1];
    }
    for (; j + 3 < end; j += 4) {
        int s0 = csr[j + 0], s1 = csr[j + 1], s2 = csr[j + 2], s3 = csr[j + 3];
        int v0 = q[(size_t)s0 * 64 + lane];
        int v1 = q[(size_t)s1 * 64 + lane];
        int v2 = q[(size_t)s2 * 64 + lane];
        int v3 = q[(size_t)s3 * 64 + lane];
        f32x2 f0 = __builtin_amdgcn_cvt_pk_f32_fp8(v0, false);
        f32x2 f1 = __builtin_amdgcn_cvt_pk_f32_fp8(v1, false);
        f32x2 f2v = __builtin_amdgcn_cvt_pk_f32_fp8(v2, false);
        f32x2 f3 = __builtin_amdgcn_cvt_pk_f32_fp8(v3, false);
        ax0 += f0[0]; ay0 += f0[1];
        ax1 += f1[0]; ay1 += f1[1];
        ax2 += f2v[0]; ay2 += f2v[1];
        ax3 += f3[0]; ay3 += f3[1];
    }
    for (; j < end; ++j) {
        int s = csr[j];
        int v = q[(size_t)s * 64 + lane];
        f32x2 f0 = __builtin_amdgcn_cvt_pk_f32_fp8(v, false);
        ax0 += f0[0]; ay0 += f0[1];
    }
    float ax = ((ax0 + ax1) + (ax2 + ax3)) + ((ax4 + ax5) + (ax6 + ax7));
    float ay = ((ay0 + ay1) + (ay2 + ay3)) + ((ay4 + ay5) + (ay6 + ay7));
    float inv = 1.0f / fmaxf((float)c, 1.0f);
    int n = w % NN;
    int fv = ((const int*)featb)[(size_t)n * 64 + lane];   // exact bf16 residual
    float hx = bs2f_lo(fv) + ax * inv;
    float hy = bs2f_hi(fv) + ay * inv;
    unsigned plo = (unsigned short)f2bs(hx);
    unsigned phi = (unsigned short)f2bs(hy);
    ((int*)ssumb)[(size_t)w * 64 + lane] = (int)((phi << 16) | plo);
}

// ======= split MFMA transform: 512-thr blocks, 8 waves, 16-node tile/wave =======

__device__ __forceinline__ void mfma_layer(const bf16x8 A[4], const short* Wlds,
                                           int g8, int c, f32x4 acc[8]) {
    #pragma unroll
    for (int kk = 0; kk < 4; ++kk) {
        #pragma unroll
        for (int t = 0; t < 8; ++t) {
            int d = t * 16 + c;
            bf16x8 B = *(const bf16x8*)&Wlds[d * 128 + ((kk * 32 + g8) ^ ((d & 7) << 3))];
            acc[t] = __builtin_amdgcn_mfma_f32_16x16x32_bf16(A[kk], B, acc[t], 0, 0, 0);
        }
    }
}

template <bool RELU, bool BIAS>
__device__ __forceinline__ void ln_block(f32x4 acc[8], const float* bias,
                                         const float* gam, const float* bet, int c) {
    float s0 = 0, s1 = 0, s2 = 0, s3 = 0, p0 = 0, p1 = 0, p2 = 0, p3 = 0;
    #pragma unroll
    for (int t = 0; t < 8; ++t) {
        if (BIAS) {
            float bb = bias[t * 16 + c];
            acc[t][0] += bb; acc[t][1] += bb;
            acc[t][2] += bb; acc[t][3] += bb;
        }
        s0 += acc[t][0]; p0 += acc[t][0] * acc[t][0];
        s1 += acc[t][1]; p1 += acc[t][1] * acc[t][1];
        s2 += acc[t][2]; p2 += acc[t][2] * acc[t][2];
        s3 += acc[t][3]; p3 += acc[t][3] * acc[t][3];
    }
    #pragma unroll
    for (int m = 1; m < 16; m <<= 1) {
        s0 += __shfl_xor(s0, m); s1 += __shfl_xor(s1, m);
        s2 += __shfl_xor(s2, m); s3 += __shfl_xor(s3, m);
        p0 += __shfl_xor(p0, m); p1 += __shfl_xor(p1, m);
        p2 += __shfl_xor(p2, m); p3 += __shfl_xor(p3, m);
    }
    const float inv = 1.0f / 128.0f;
    float mu0 = s0 * inv, mu1 = s1 * inv, mu2 = s2 * inv, mu3 = s3 * inv;
    float r0 = rsqrtf(p0 * inv - mu0 * mu0 + EPSF);
    float r1 = rsqrtf(p1 * inv - mu1 * mu1 + EPSF);
    float r2 = rsqrtf(p2 * inv - mu2 * mu2 + EPSF);
    float r3 = rsqrtf(p3 * inv - mu3 * mu3 + EPSF);
    #pragma unroll
    for (int t = 0; t < 8; ++t) {
        float gg = gam[t * 16 + c], bb = bet[t * 16 + c];
        float v0 = (acc[t][0] - mu0) * r0 * gg + bb;
        float v1 = (acc[t][1] - mu1) * r1 * gg + bb;
        float v2 = (acc[t][2] - mu2) * r2 * gg + bb;
        float v3 = (acc[t][3] - mu3) * r3 * gg + bb;
        if (RELU) {
            v0 = fmaxf(v0, 0.f); v1 = fmaxf(v1, 0.f);
            v2 = fmaxf(v2, 0.f); v3 = fmaxf(v3, 0.f);
        }
        acc[t][0] = v0; acc[t][1] = v1;
        acc[t][2] = v2; acc[t][3] = v3;
    }
}

__device__ __forceinline__ void store_ht(const f32x4 acc[8], short* myht, int g, int c) {
    #pragma unroll
    for (int t = 0; t < 8; ++t) {
        int col = t * 16 + c;
        #pragma unroll
        for (int qq = 0; qq < 4; ++qq) {
            int row = g * 4 + qq;
            myht[row * 128 + (col ^ ((row & 7) << 3))] = f2bs(acc[t][qq]);
        }
    }
}

__device__ __forceinline__ void ht_to_global(const short* myht, short* gout, int g, int c) {
    #pragma unroll
    for (int cc = 0; cc < 4; ++cc) {
        int row = cc * 4 + g;
        int col0 = c * 8;
        bf16x8 v = *(const bf16x8*)&myht[row * 128 + (col0 ^ ((row & 7) << 3))];
        *(bf16x8*)&gout[row * FF + col0] = v;
    }
}

// layer 1: X1 = relu(LN(h @ W0 + b0)), in-place over hbuf
__global__ __launch_bounds__(512)
void fused_l1(short* hbuf,
              const float* __restrict__ W0, const float* __restrict__ b0,
              const float* __restrict__ ln_g, const float* __restrict__ ln_b) {
    __shared__ short W0t[FF * DD];        // 32 KiB
    __shared__ short ht[8][16 * DD];      // 32 KiB
    __shared__ float b0s[DD], lgs[DD], lbs[DD];

    const int r = blockIdx.y;
    const int tid = threadIdx.x;

    for (int i = tid; i < FF * DD; i += 512) {
        int k = i >> 7, d = i & 127;
        W0t[d * 128 + (k ^ ((d & 7) << 3))] = f2bs(W0[(size_t)r * FF * DD + i]);
    }
    if (tid < DD) {
        b0s[tid] = b0[r * DD + tid];
        lgs[tid] = ln_g[r * DD + tid];
        lbs[tid] = ln_b[r * DD + tid];
    }
    __syncthreads();

    const int wv = tid >> 6, ln = tid & 63;
    const int g = ln >> 4, c = ln & 15;
    const int g8 = g * 8;
    short* myht = ht[wv];

    for (int tile = blockIdx.x * 8 + wv; tile < NTILES; tile += gridDim.x * 8) {
        const int nbase = tile * 16;
        bf16x8 A[4];
        {
            const short* sp = hbuf + ((size_t)r * NN + nbase + c) * FF;
            #pragma unroll
            for (int kk = 0; kk < 4; ++kk)
                A[kk] = *(const bf16x8*)(sp + kk * 32 + g8);
        }
        f32x4 acc[8];
        #pragma unroll
        for (int t = 0; t < 8; ++t) acc[t] = (f32x4){0.f, 0.f, 0.f, 0.f};
        mfma_layer(A, W0t, g8, c, acc);
        ln_block<true, true>(acc, b0s, lgs, lbs, c);
        store_ht(acc, myht, g, c);
        ht_to_global(myht, hbuf + ((size_t)r * NN + nbase) * FF, g, c);
    }
}

// layer 2 + final LN: h = LN(relu(LN(X1 @ W1 + b1))), in-place over hbuf
__global__ __launch_bounds__(512)
void fused_l2(short* hbuf,
              const float* __restrict__ W1, const float* __restrict__ b1,
              const float* __restrict__ ln_g, const float* __restrict__ ln_b,
              const float* __restrict__ LN_g, const float* __restrict__ LN_b) {
    __shared__ short W1t[DD * DD];        // 32 KiB
    __shared__ short ht[8][16 * DD];      // 32 KiB
    __shared__ float b1s[DD], lgs[DD], lbs[DD], Lgs[DD], Lbs[DD];

    const int r = blockIdx.y;
    const int tid = threadIdx.x;

    for (int i = tid; i < DD * DD; i += 512) {
        int k = i >> 7, d = i & 127;
        W1t[d * 128 + (k ^ ((d & 7) << 3))] = f2bs(W1[(size_t)r * DD * DD + i]);
    }
    if (tid < DD) {
        b1s[tid] = b1[r * DD + tid];
        lgs[tid] = ln_g[r * DD + tid];
        lbs[tid] = ln_b[r * DD + tid];
        Lgs[tid] = LN_g[tid];
        Lbs[tid] = LN_b[tid];
    }
    __syncthreads();

    const int wv = tid >> 6, ln = tid & 63;
    const int g = ln >> 4, c = ln & 15;
    const int g8 = g * 8;
    short* myht = ht[wv];

    for (int tile = blockIdx.x * 8 + wv; tile < NTILES; tile += gridDim.x * 8) {
        const int nbase = tile * 16;
        bf16x8 A[4];
        {
            const short* sp = hbuf + ((size_t)r * NN + nbase + c) * FF;
            #pragma unroll
            for (int kk = 0; kk < 4; ++kk)
                A[kk] = *(const bf16x8*)(sp + kk * 32 + g8);
        }
        f32x4 acc[8];
        #pragma unroll
        for (int t = 0; t < 8; ++t) acc[t] = (f32x4){0.f, 0.f, 0.f, 0.f};
        mfma_layer(A, W1t, g8, c, acc);
        ln_block<true, true>(acc, b1s, lgs, lbs, c);
        ln_block<false, false>(acc, nullptr, Lgs, Lbs, c);
        store_ht(acc, myht, g, c);
        ht_to_global(myht, hbuf + ((size_t)r * NN + nbase) * FF, g, c);
    }
}

// ---------- attention scores: e = tanh(h @ Wa1) . Wa2 (transposed mfma) ----------
__global__ __launch_bounds__(256)
void attn_score(const short* __restrict__ hbuf,
                const float* __restrict__ Wa1, const float* __restrict__ Wa2,
                float* __restrict__ evec) {
    __shared__ short Wa1t[RR][AA * DD];   // 48 KiB, [r][a][k] swizzled
    __shared__ float wa2s[RR][AA];

    const int tid = threadIdx.x;
    for (int i = tid; i < RR * DD * AA; i += 256) {
        int r2 = i >> 13;                  // / 8192
        int rem = i & 8191;
        int k = rem >> 6, a = rem & 63;
        Wa1t[r2][a * 128 + (k ^ ((a & 7) << 3))] = f2bs(Wa1[i]);
    }
    if (tid < RR * AA) wa2s[tid >> 6][tid & 63] = Wa2[tid];
    __syncthreads();

    const int wv = tid >> 6, ln = tid & 63;
    const int col = ln & 15, g = ln >> 4;
    const int g8 = g * 8, g4 = g * 4;

    for (int idx = blockIdx.x * 4 + wv; idx < RR * NTILES; idx += gridDim.x * 4) {
        int r = idx / NTILES;
        int tile = idx - r * NTILES;
        int nbase = tile * 16;
        const short* hrow = hbuf + ((size_t)r * NN + nbase + col) * FF;

        f32x4 acc[4];
        #pragma unroll
        for (int t = 0; t < 4; ++t) acc[t] = (f32x4){0.f, 0.f, 0.f, 0.f};
        #pragma unroll
        for (int kk = 0; kk < 4; ++kk) {
            bf16x8 Bh = *(const bf16x8*)(hrow + kk * 32 + g8);
            #pragma unroll
            for (int t = 0; t < 4; ++t) {
                int a_ = t * 16 + col;
                bf16x8 Wf = *(const bf16x8*)&Wa1t[r][a_ * 128 + ((kk * 32 + g8) ^ ((a_ & 7) << 3))];
                acc[t] = __builtin_amdgcn_mfma_f32_16x16x32_bf16(Wf, Bh, acc[t], 0, 0, 0);
            }
        }
        float e = 0.f;
        #pragma unroll
        for (int t = 0; t < 4; ++t) {
            f32x4 wv2 = *(const f32x4*)&wa2s[r][t * 16 + g4];
            e += ftanh(acc[t][0]) * wv2[0] + ftanh(acc[t][1]) * wv2[1]
               + ftanh(acc[t][2]) * wv2[2] + ftanh(acc[t][3]) * wv2[3];
        }
        e += __shfl_xor(e, 16);
        e += __shfl_xor(e, 32);
        if (ln < 16) evec[(size_t)r * NN + nbase + ln] = e;
    }
}

// ---------------- softmax over relations + weighted combine ----------------
__global__ __launch_bounds__(256)
void combine_kernel(const short* __restrict__ hfb,
                    const float* __restrict__ evec,
                    float* __restrict__ out) {
    int gid = blockIdx.x * blockDim.x + threadIdx.x;
    if (gid >= NN * 64) return;
    int n = gid >> 6, j = gid & 63;
    float e0 = evec[n], e1 = evec[NN + n], e2 = evec[2 * NN + n];
    float m = fmaxf(e0, fmaxf(e1, e2));
    float w0 = __expf(e0 - m), w1 = __expf(e1 - m), w2 = __expf(e2 - m);
    float inv = 1.0f / (w0 + w1 + w2);
    w0 *= inv; w1 *= inv; w2 *= inv;
    const int* h0 = (const int*)hfb + (size_t)n * 64;
    const int* h1 = (const int*)hfb + ((size_t)NN + n) * 64;
    const int* h2 = (const int*)hfb + ((size_t)2 * NN + n) * 64;
    int a = h0[j], b = h1[j], d = h2[j];
    float2 o;
    o.x = w0 * bs2f_lo(a) + w1 * bs2f_lo(b) + w2 * bs2f_lo(d);
    o.y = w0 * bs2f_hi(a) + w1 * bs2f_hi(b) + w2 * bs2f_hi(d);
    ((float2*)out)[(size_t)n * 64 + j] = o;
}

extern "C" void kernel_launch(void* const* d_in, const int* in_sizes, int n_in,
                              void* d_out, int out_size, void* d_ws, size_t ws_size,
                              hipStream_t stream) {
    const float* feat = (const float*)d_in[0];
    const int*   src  = (const int*)d_in[1];
    const int*   dst  = (const int*)d_in[2];
    const float* W0   = (const float*)d_in[3];
    const float* b0   = (const float*)d_in[4];
    const float* W1   = (const float*)d_in[5];
    const float* b1   = (const float*)d_in[6];
    const float* ln_g = (const float*)d_in[7];
    const float* ln_b = (const float*)d_in[8];
    const float* LN_g = (const float*)d_in[9];
    const float* LN_b = (const float*)d_in[10];
    const float* Wa1  = (const float*)d_in[11];
    const float* Wa2  = (const float*)d_in[12];
    float* out = (float*)d_out;

    // workspace layout
    short*    ssumb  = (short*)d_ws;                        // RN*FF bf16 (38.4 MB)
    short*    featb  = ssumb + (size_t)RN * FF;             // NN*FF bf16 (12.8 MB)
    int*      featq  = (int*)(featb + (size_t)NN * FF);     // NN*FF fp8 (6.4 MB)
    int*      cnt    = featq + (size_t)NN * 32;             // RN (written by scatterB)
    int*      off    = cnt + RN;                            // RN (written by scatterB)
    int*      csr    = off + RN;                            // RE
    float*    evec   = (float*)(csr + RE);                  // RN
    int*      bcnt   = (int*)(evec + RN);                   // NBK
    int*      bstart = bcnt + NBK;                          // NBK
    int*      boff   = bstart + NBK;                        // NBK
    unsigned* bpair  = (unsigned*)(boff + NBK);             // RE (9.6 MB)
    int*      bhist  = (int*)(bpair + RE);                  // NEBLK*NBK (1.37 MB)

    feat2both<<<(NN * 16 + 255) / 256, 256, 0, stream>>>(feat, featb, featq);
    hipMemsetAsync(bcnt, 0, (size_t)NBK * sizeof(int), stream);
    count_kernel<<<NEBLK, 256, 0, stream>>>(dst, bcnt, bhist);
    bscan_kernel<<<1, 256, 0, stream>>>(bcnt, bstart, boff);
    bscatterA<<<NEBLK, 256, 0, stream>>>(src, dst, bhist, boff, bpair);
    scatterB<<<NBK, 256, 0, stream>>>(bpair, bstart, bcnt, off, cnt, csr);
    gather_kernel<<<(RN * 64 + 255) / 256, 256, 0, stream>>>(featb, featq, csr, off, cnt, ssumb);

    const int GX = (NTILES + 7) / 8;                        // 391 blocks/relation
    fused_l1<<<dim3(GX, RR), 512, 0, stream>>>(ssumb, W0, b0, ln_g, ln_b);
    fused_l2<<<dim3(GX, RR), 512, 0, stream>>>(ssumb, W1, b1, ln_g, ln_b, LN_g, LN_b);
    attn_score<<<512, 256, 0, stream>>>(ssumb, Wa1, Wa2, evec);
    combine_kernel<<<(NN * 64 + 255) / 256, 256, 0, stream>>>(ssumb, evec, out);
}